// Round 2
// baseline (140.902 us; speedup 1.0000x reference)
//
#include <hip/hip_runtime.h>

// DCNv2, fp32 in/out, all matmul-shaped work on bf16 MFMA.
// Round 2: barrier-free fused kernel. Sampling/im2col lanes are assigned so
// each lane produces its MFMA B-fragment directly in registers
// (px = lane&15, cin octets (lane>>4)*8 and 32+(lane>>4)*8) — no LDS staging
// for B, no per-kk __syncthreads. Only LDS: 18x64 offset tile, written and
// read by the same wave (per-column ownership) -> no barrier at all.
//  - pre_kernel: x NCHW -> xT_hi/xT_lo bf16 NHWC (split-bf16) + weight A-frags
//  - fused_dcn_kernel: offset conv (im2col GEMM, 3-term split-bf16) ->
//    offsets in LDS -> bilinear sample into B-frags -> deform GEMM.
// ws: xThi 8388608 | xTlo 8388608 | wdA 73728 | woAhi 36864 | woAlo 36864

#define BATCH 4
#define CIN   64
#define COUT  64
#define HH    128
#define WW    128
#define HWPIX (HH*WW)

typedef __attribute__((ext_vector_type(8))) short short8;   // 8 bf16 (4 VGPRs)
typedef __attribute__((ext_vector_type(4))) float floatx4;  // MFMA C/D

__device__ __forceinline__ unsigned short f2bf(float f) {   // RNE f32->bf16
  unsigned int u = __float_as_uint(f);
  unsigned int r = u + 0x7fffu + ((u >> 16) & 1u);
  return (unsigned short)(r >> 16);
}
__device__ __forceinline__ float bf2f(unsigned short h) { return __uint_as_float(((unsigned int)h) << 16); }
__device__ __forceinline__ float lo16f(unsigned int u) { return __uint_as_float(u << 16); }
__device__ __forceinline__ float hi16f(unsigned int u) { return __uint_as_float(u & 0xffff0000u); }

__device__ __forceinline__ unsigned int bilin2(unsigned int u00, unsigned int u01,
                                               unsigned int u10, unsigned int u11,
                                               float w00, float w01, float w10, float w11) {
  float lo = w00 * lo16f(u00) + w01 * lo16f(u01) + w10 * lo16f(u10) + w11 * lo16f(u11);
  float hi = w00 * hi16f(u00) + w01 * hi16f(u01) + w10 * hi16f(u10) + w11 * hi16f(u11);
  return (unsigned int)f2bf(lo) | ((unsigned int)f2bf(hi) << 16);
}

// Fused preprocessing:
//  blocks [0,4096):  x fp32 NCHW -> xThi/xTlo bf16 [b][px][cin]
//  blocks [4096,4312): weight prep
//    wdA[kk][kc2][ct4][lane][j] bf16 (A-frag, 36864 elems);
//    woAhi/lo[kk][kc2][ct2][lane][j] bf16 (A-frag, M=32 rows, rows>=18 zero)
__global__ __launch_bounds__(256) void pre_kernel(const float* __restrict__ x,
                                                  const float* __restrict__ wo,
                                                  const float* __restrict__ wd,
                                                  unsigned short* __restrict__ xThi,
                                                  unsigned short* __restrict__ xTlo,
                                                  unsigned short* __restrict__ wdA,
                                                  unsigned short* __restrict__ woAhi,
                                                  unsigned short* __restrict__ woAlo) {
  int tid = threadIdx.x;
  if (blockIdx.x < 4096) {
    // ---- transpose + split-bf16 ----
    __shared__ float tile[32][33];   // [c_local][p_local]
    int t = blockIdx.x;
    int b = t >> 10, rem = t & 1023;
    int c0 = (rem >> 9) * 32, p0 = (rem & 511) * 32;
    int tx = tid & 31, ty = tid >> 5;      // (32,8)
    const float* xb = x + (size_t)b * CIN * HWPIX;
    size_t boff = (size_t)b * HWPIX * CIN;
#pragma unroll
    for (int i = 0; i < 4; i++)
      tile[ty + i * 8][tx] = xb[(size_t)(c0 + ty + i * 8) * HWPIX + p0 + tx];
    __syncthreads();
#pragma unroll
    for (int i = 0; i < 2; i++) {
      int tt = tid + i * 256;       // 0..511 = 32 rows * 16 cin-pairs
      int row = tt >> 4;
      int cp = tt & 15;
      float v0 = tile[cp * 2][row], v1 = tile[cp * 2 + 1][row];
      unsigned short h0 = f2bf(v0), h1 = f2bf(v1);
      unsigned short l0 = f2bf(v0 - bf2f(h0)), l1 = f2bf(v1 - bf2f(h1));
      size_t o = boff + (size_t)(p0 + row) * CIN + c0 + cp * 2;
      *(ushort2*)&xThi[o] = make_ushort2(h0, h1);
      *(ushort2*)&xTlo[o] = make_ushort2(l0, l1);
    }
  } else {
    // ---- weight prep ----
    int t = (blockIdx.x - 4096) * 256 + tid;
    if (t < 36864) {
      int j = t & 7, lane = (t >> 3) & 63, ct = (t >> 9) & 3, kc = (t >> 11) & 1, kk = t >> 12;
      int cout = ct * 16 + (lane & 15);
      int cin  = kc * 32 + (lane >> 4) * 8 + j;
      wdA[t] = f2bf(wd[(size_t)(cout * CIN + cin) * 9 + kk]);
    }
    int t2 = t - 36864;
    if (t2 >= 0 && t2 < 18432) {
      int j = t2 & 7, lane = (t2 >> 3) & 63, ct = (t2 >> 9) & 1, kc = (t2 >> 10) & 1, kk = t2 >> 11;
      int cout = ct * 16 + (lane & 15);          // conv channel 0..31 (valid < 18)
      int cin  = kc * 32 + (lane >> 4) * 8 + j;
      float v = (cout < 18) ? wo[(size_t)(cout * CIN + cin) * 9 + kk] : 0.f;
      unsigned short h = f2bf(v);
      woAhi[t2] = h;
      woAlo[t2] = f2bf(v - bf2f(h));
    }
  }
}

// Fused offset-conv + deform GEMM, barrier-free.
// One block = 64 px tile (b, y, x0..x0+63); 4 waves, wave w owns px
// [x0+16w, x0+16w+16). Lane l: col = l&15 (px), g = l>>4 (cin octet group:
// cin g*8..g*8+8 and 32+g*8..+8) — exactly the mfma_16x16x32 B-frag layout,
// so sampled values go straight from registers into MFMA.
__global__ __launch_bounds__(256) void fused_dcn_kernel(const unsigned short* __restrict__ xThi,
                                                        const unsigned short* __restrict__ xTlo,
                                                        const unsigned short* __restrict__ woAhi,
                                                        const unsigned short* __restrict__ woAlo,
                                                        const unsigned short* __restrict__ wdA,
                                                        float* __restrict__ out) {
  __shared__ float offL[18 * 64];          // 4.5 KB; [chan][px_local], per-wave columns

  int tid = threadIdx.x;
  int hw = blockIdx.x;
  int bid = (hw & 7) * 128 + (hw >> 3);    // XCD-contiguous y bands
  int b = bid >> 8, r = bid & 255, y = r >> 1, x0 = (r & 1) << 6;

  int lane = tid & 63, w = tid >> 6;
  int col = lane & 15, g = lane >> 4;
  int wcol = w * 16 + col;                 // px local to block
  int px = x0 + wcol;                      // this lane's pixel (B-frag col & output col)
  int coff = g * 8;                        // first cin octet; second at +32

  const unsigned short* xhib = xThi + (size_t)b * HWPIX * CIN;
  const unsigned short* xlob = xTlo + (size_t)b * HWPIX * CIN;

  // ================= Phase A: offset conv (im2col GEMM) =================
  floatx4 oacc[2];
  oacc[0] = (floatx4){0.f, 0.f, 0.f, 0.f};
  oacc[1] = (floatx4){0.f, 0.f, 0.f, 0.f};

#pragma unroll 1
  for (int kk = 0; kk < 9; kk++) {
    int ys = y - 1 + kk / 3;
    int xs = px - 1 + kk % 3;
    bool valid = (ys >= 0) && (ys < HH) && (xs >= 0) && (xs < WW);
    uint4 h0 = {0, 0, 0, 0}, h1 = {0, 0, 0, 0}, l0 = {0, 0, 0, 0}, l1 = {0, 0, 0, 0};
    if (valid) {
      const unsigned short* ph = xhib + (size_t)(ys * WW + xs) * CIN + coff;
      const unsigned short* pl = xlob + (size_t)(ys * WW + xs) * CIN + coff;
      h0 = *(const uint4*)ph; h1 = *(const uint4*)(ph + 32);
      l0 = *(const uint4*)pl; l1 = *(const uint4*)(pl + 32);
    }
    short8 bh0 = *(short8*)&h0, bh1 = *(short8*)&h1;
    short8 bl0 = *(short8*)&l0, bl1 = *(short8*)&l1;
    const short8* Ah = (const short8*)(woAhi + (size_t)kk * 2048);
    const short8* Al = (const short8*)(woAlo + (size_t)kk * 2048);
#pragma unroll
    for (int ct = 0; ct < 2; ct++) {
      short8 ah0 = Ah[ct * 64 + lane], ah1 = Ah[128 + ct * 64 + lane];
      short8 al0 = Al[ct * 64 + lane], al1 = Al[128 + ct * 64 + lane];
      oacc[ct] = __builtin_amdgcn_mfma_f32_16x16x32_bf16(ah0, bh0, oacc[ct], 0, 0, 0);
      oacc[ct] = __builtin_amdgcn_mfma_f32_16x16x32_bf16(ah0, bl0, oacc[ct], 0, 0, 0);
      oacc[ct] = __builtin_amdgcn_mfma_f32_16x16x32_bf16(al0, bh0, oacc[ct], 0, 0, 0);
      oacc[ct] = __builtin_amdgcn_mfma_f32_16x16x32_bf16(ah1, bh1, oacc[ct], 0, 0, 0);
      oacc[ct] = __builtin_amdgcn_mfma_f32_16x16x32_bf16(ah1, bl1, oacc[ct], 0, 0, 0);
      oacc[ct] = __builtin_amdgcn_mfma_f32_16x16x32_bf16(al1, bh1, oacc[ct], 0, 0, 0);
    }
  }

  // Scatter offsets to LDS. D layout: col=lane&15 (px), row=(lane>>4)*4+rr.
  // Wave w writes only columns [16w,16w+16) and reads only those columns
  // below -> same-wave ordering, no __syncthreads needed.
  {
    int rowb = g * 4;
#pragma unroll
    for (int ct = 0; ct < 2; ct++)
#pragma unroll
      for (int rr = 0; rr < 4; rr++) {
        int row = ct * 16 + rowb + rr;
        if (row < 18) offL[row * 64 + wcol] = oacc[ct][rr];
      }
  }

  // ================= Phase B: deform sample + GEMM =================
  floatx4 acc[4];
#pragma unroll
  for (int ct = 0; ct < 4; ct++) acc[ct] = (floatx4){0.f, 0.f, 0.f, 0.f};

#pragma unroll 1
  for (int kk = 0; kk < 9; kk++) {
    // ---- sample this lane's 16 cin (2 octets) for its px ----
    float dy = offL[(2 * kk) * 64 + wcol];
    float dx = offL[(2 * kk + 1) * 64 + wcol];
    float ys = (float)(y - 1 + kk / 3) + dy;
    float xs = (float)(px - 1 + kk % 3) + dx;
    float y0f = floorf(ys), x0f = floorf(xs);
    float wy = ys - y0f, wx = xs - x0f;
    int iy0 = (int)y0f, ix0 = (int)x0f;
    int iy1 = iy0 + 1, ix1 = ix0 + 1;
    float w00 = (1.f - wy) * (1.f - wx), w01 = (1.f - wy) * wx;
    float w10 = wy * (1.f - wx), w11 = wy * wx;
    bool vy0 = (iy0 >= 0) && (iy0 < HH), vy1 = (iy1 >= 0) && (iy1 < HH);
    bool vx0 = (ix0 >= 0) && (ix0 < WW), vx1 = (ix1 >= 0) && (ix1 < WW);
    if (!(vy0 && vx0)) w00 = 0.f;
    if (!(vy0 && vx1)) w01 = 0.f;
    if (!(vy1 && vx0)) w10 = 0.f;
    if (!(vy1 && vx1)) w11 = 0.f;
    int cy0 = min(max(iy0, 0), HH - 1), cy1 = min(max(iy1, 0), HH - 1);
    int cx0 = min(max(ix0, 0), WW - 1), cx1 = min(max(ix1, 0), WW - 1);
    const unsigned short* q00 = xhib + (size_t)(cy0 * WW + cx0) * CIN + coff;
    const unsigned short* q01 = xhib + (size_t)(cy0 * WW + cx1) * CIN + coff;
    const unsigned short* q10 = xhib + (size_t)(cy1 * WW + cx0) * CIN + coff;
    const unsigned short* q11 = xhib + (size_t)(cy1 * WW + cx1) * CIN + coff;
    uint4 a00 = *(const uint4*)q00, a01 = *(const uint4*)q01;
    uint4 a10 = *(const uint4*)q10, a11 = *(const uint4*)q11;
    uint4 b00 = *(const uint4*)(q00 + 32), b01 = *(const uint4*)(q01 + 32);
    uint4 b10 = *(const uint4*)(q10 + 32), b11 = *(const uint4*)(q11 + 32);
    uint4 o0, o1;
    o0.x = bilin2(a00.x, a01.x, a10.x, a11.x, w00, w01, w10, w11);
    o0.y = bilin2(a00.y, a01.y, a10.y, a11.y, w00, w01, w10, w11);
    o0.z = bilin2(a00.z, a01.z, a10.z, a11.z, w00, w01, w10, w11);
    o0.w = bilin2(a00.w, a01.w, a10.w, a11.w, w00, w01, w10, w11);
    o1.x = bilin2(b00.x, b01.x, b10.x, b11.x, w00, w01, w10, w11);
    o1.y = bilin2(b00.y, b01.y, b10.y, b11.y, w00, w01, w10, w11);
    o1.z = bilin2(b00.z, b01.z, b10.z, b11.z, w00, w01, w10, w11);
    o1.w = bilin2(b00.w, b01.w, b10.w, b11.w, w00, w01, w10, w11);
    short8 bv0 = *(short8*)&o0, bv1 = *(short8*)&o1;

    // ---- MFMA ----
    const short8* Ap = (const short8*)(wdA + (size_t)kk * 4096);
#pragma unroll
    for (int ct = 0; ct < 4; ct++) {
      short8 a0 = Ap[ct * 64 + lane];
      short8 a1 = Ap[256 + ct * 64 + lane];
      acc[ct] = __builtin_amdgcn_mfma_f32_16x16x32_bf16(a0, bv0, acc[ct], 0, 0, 0);
      acc[ct] = __builtin_amdgcn_mfma_f32_16x16x32_bf16(a1, bv1, acc[ct], 0, 0, 0);
    }
  }

  // D: col = lane&15 (px in wave tile), row = (lane>>4)*4 + reg (cout in ct tile)
  int rowb = g * 4;
  float* outb = out + (size_t)b * COUT * HWPIX + y * WW + px;
#pragma unroll
  for (int ct = 0; ct < 4; ct++)
#pragma unroll
    for (int rr = 0; rr < 4; rr++)
      outb[(size_t)(ct * 16 + rowb + rr) * HWPIX] = acc[ct][rr];
}

extern "C" void kernel_launch(void* const* d_in, const int* in_sizes, int n_in,
                              void* d_out, int out_size, void* d_ws, size_t ws_size,
                              hipStream_t stream) {
  const float* x  = (const float*)d_in[0];
  const float* wo = (const float*)d_in[1];
  const float* wd = (const float*)d_in[2];
  float* out = (float*)d_out;

  char* wsb = (char*)d_ws;
  unsigned short* xThi  = (unsigned short*)wsb;                         // 8,388,608 B
  unsigned short* xTlo  = (unsigned short*)(wsb + 8388608);             // 8,388,608 B
  unsigned short* wdA   = (unsigned short*)(wsb + 16777216);            // 73,728 B
  unsigned short* woAhi = (unsigned short*)(wsb + 16777216 + 73728);    // 36,864 B
  unsigned short* woAlo = (unsigned short*)(wsb + 16850944 + 36864);    // 36,864 B

  pre_kernel<<<dim3(4096 + 216), dim3(256), 0, stream>>>(x, wo, wd, xThi, xTlo, wdA, woAhi, woAlo);
  fused_dcn_kernel<<<dim3(BATCH * HWPIX / 64), dim3(256), 0, stream>>>(xThi, xTlo, woAhi, woAlo, wdA, out);
}

// Round 3
// 115.485 us; speedup vs baseline: 1.2201x; 1.2201x over previous
//
#include <hip/hip_runtime.h>

// DCNv2, fp32 in/out, all matmul-shaped work on bf16 MFMA.
// Round 3: R1 fused structure (barriered, LDS B-frag staging — proven 47.5us)
// + software-pipelined kk loops (issue kk+1 loads before consuming kk; T14)
// + XOR swizzle on B-frag LDS stores/reads (kills 4-way write bank conflict).
//  - pre_kernel: x NCHW -> xT_hi/xT_lo bf16 NHWC (split-bf16) + weight A-frags
//  - fused_dcn_kernel: offset conv (im2col GEMM, 3-term split-bf16) ->
//    offsets in LDS -> bilinear sample -> LDS B-frags -> deform GEMM.
// ws: xThi 8388608 | xTlo 8388608 | wdA 73728 | woAhi 36864 | woAlo 36864

#define BATCH 4
#define CIN   64
#define COUT  64
#define HH    128
#define WW    128
#define HWPIX (HH*WW)

typedef __attribute__((ext_vector_type(8))) short short8;   // 8 bf16 (4 VGPRs)
typedef __attribute__((ext_vector_type(4))) float floatx4;  // MFMA C/D

__device__ __forceinline__ unsigned short f2bf(float f) {   // RNE f32->bf16
  unsigned int u = __float_as_uint(f);
  unsigned int r = u + 0x7fffu + ((u >> 16) & 1u);
  return (unsigned short)(r >> 16);
}
__device__ __forceinline__ float bf2f(unsigned short h) { return __uint_as_float(((unsigned int)h) << 16); }
__device__ __forceinline__ float lo16f(unsigned int u) { return __uint_as_float(u << 16); }
__device__ __forceinline__ float hi16f(unsigned int u) { return __uint_as_float(u & 0xffff0000u); }

__device__ __forceinline__ unsigned int bilin2(unsigned int u00, unsigned int u01,
                                               unsigned int u10, unsigned int u11,
                                               float w00, float w01, float w10, float w11) {
  float lo = w00 * lo16f(u00) + w01 * lo16f(u01) + w10 * lo16f(u10) + w11 * lo16f(u11);
  float hi = w00 * hi16f(u00) + w01 * hi16f(u01) + w10 * hi16f(u10) + w11 * hi16f(u11);
  return (unsigned int)f2bf(lo) | ((unsigned int)f2bf(hi) << 16);
}

// LDS byte-offset swizzle: fold bits 9-10 into bits 4-5. Writes at +512/+1024
// strides (the 4 si slices) land on distinct bank quads; reads become 2-way
// aliased (free). Same function on store & read side -> consistent storage.
__device__ __forceinline__ int swz(int a) { return a ^ (((a >> 9) & 3) << 4); }

// Fused preprocessing:
//  blocks [0,4096):  x fp32 NCHW -> xThi/xTlo bf16 [b][px][cin]
//  blocks [4096,4312): weight prep
__global__ __launch_bounds__(256) void pre_kernel(const float* __restrict__ x,
                                                  const float* __restrict__ wo,
                                                  const float* __restrict__ wd,
                                                  unsigned short* __restrict__ xThi,
                                                  unsigned short* __restrict__ xTlo,
                                                  unsigned short* __restrict__ wdA,
                                                  unsigned short* __restrict__ woAhi,
                                                  unsigned short* __restrict__ woAlo) {
  int tid = threadIdx.x;
  if (blockIdx.x < 4096) {
    __shared__ float tile[32][33];   // [c_local][p_local]
    int t = blockIdx.x;
    int b = t >> 10, rem = t & 1023;
    int c0 = (rem >> 9) * 32, p0 = (rem & 511) * 32;
    int tx = tid & 31, ty = tid >> 5;      // (32,8)
    const float* xb = x + (size_t)b * CIN * HWPIX;
    size_t boff = (size_t)b * HWPIX * CIN;
#pragma unroll
    for (int i = 0; i < 4; i++)
      tile[ty + i * 8][tx] = xb[(size_t)(c0 + ty + i * 8) * HWPIX + p0 + tx];
    __syncthreads();
#pragma unroll
    for (int i = 0; i < 2; i++) {
      int tt = tid + i * 256;       // 0..511 = 32 rows * 16 cin-pairs
      int row = tt >> 4;
      int cp = tt & 15;
      float v0 = tile[cp * 2][row], v1 = tile[cp * 2 + 1][row];
      unsigned short h0 = f2bf(v0), h1 = f2bf(v1);
      unsigned short l0 = f2bf(v0 - bf2f(h0)), l1 = f2bf(v1 - bf2f(h1));
      size_t o = boff + (size_t)(p0 + row) * CIN + c0 + cp * 2;
      *(ushort2*)&xThi[o] = make_ushort2(h0, h1);
      *(ushort2*)&xTlo[o] = make_ushort2(l0, l1);
    }
  } else {
    int t = (blockIdx.x - 4096) * 256 + tid;
    if (t < 36864) {
      int j = t & 7, lane = (t >> 3) & 63, ct = (t >> 9) & 3, kc = (t >> 11) & 1, kk = t >> 12;
      int cout = ct * 16 + (lane & 15);
      int cin  = kc * 32 + (lane >> 4) * 8 + j;
      wdA[t] = f2bf(wd[(size_t)(cout * CIN + cin) * 9 + kk]);
    }
    int t2 = t - 36864;
    if (t2 >= 0 && t2 < 18432) {
      int j = t2 & 7, lane = (t2 >> 3) & 63, ct = (t2 >> 9) & 1, kc = (t2 >> 10) & 1, kk = t2 >> 11;
      int cout = ct * 16 + (lane & 15);          // conv channel 0..31 (valid < 18)
      int cin  = kc * 32 + (lane >> 4) * 8 + j;
      float v = (cout < 18) ? wo[(size_t)(cout * CIN + cin) * 9 + kk] : 0.f;
      unsigned short h = f2bf(v);
      woAhi[t2] = h;
      woAlo[t2] = f2bf(v - bf2f(h));
    }
  }
}

// Fused offset-conv + deform GEMM, software-pipelined.
// Block: 64 px tile (b, y, x0..x0+63), 256 thr = 4 waves.
// Staging view: p1 = tid>>2 (px 0..63), si = tid&3 (16-cin slice).
// MFMA view: wave w, lane.
__global__ __launch_bounds__(256) void fused_dcn_kernel(const unsigned short* __restrict__ xThi,
                                                        const unsigned short* __restrict__ xTlo,
                                                        const unsigned short* __restrict__ woAhi,
                                                        const unsigned short* __restrict__ woAlo,
                                                        const unsigned short* __restrict__ wdA,
                                                        float* __restrict__ out) {
  __shared__ unsigned short sBhi[4096];    // 8 KB; A: im2col hi; B: sampled frags
  __shared__ unsigned short sBlo[4096];    // 8 KB; A only: im2col lo
  __shared__ float offL[18 * 64];          // 4.5 KB

  int tid = threadIdx.x;
  int hw = blockIdx.x;
  int bid = (hw & 7) * 128 + (hw >> 3);    // XCD-contiguous y bands
  int b = bid >> 8, r = bid & 255, y = r >> 1, x0 = (r & 1) << 6;

  int p1 = tid >> 2, si = tid & 3;
  int lane = tid & 63, w = tid >> 6;

  const unsigned short* xhib = xThi + (size_t)b * HWPIX * CIN;
  const unsigned short* xlob = xTlo + (size_t)b * HWPIX * CIN;

  // B-frag staging addresses (byte offsets), swizzled once.
  int wq = p1 >> 4, iq = p1 & 15;
  int kcd = si >> 1, qb = si & 1;
  int wb0 = ((((wq * 2 + kcd) * 64) + qb * 32 + iq) * 8) * 2;
  int wb1 = wb0 + 256;
  unsigned short* stHi0 = (unsigned short*)((char*)sBhi + swz(wb0));
  unsigned short* stHi1 = (unsigned short*)((char*)sBhi + swz(wb1));
  unsigned short* stLo0 = (unsigned short*)((char*)sBlo + swz(wb0));
  unsigned short* stLo1 = (unsigned short*)((char*)sBlo + swz(wb1));
  int rb0 = (w * 2 + 0) * 1024 + lane * 16;
  int rb1 = (w * 2 + 1) * 1024 + lane * 16;
  const short8* rdHi0 = (const short8*)((const char*)sBhi + swz(rb0));
  const short8* rdHi1 = (const short8*)((const char*)sBhi + swz(rb1));
  const short8* rdLo0 = (const short8*)((const char*)sBlo + swz(rb0));
  const short8* rdLo1 = (const short8*)((const char*)sBlo + swz(rb1));

  int xp = x0 + p1;

  // ================= Phase A: offset conv (pipelined) =================
  floatx4 oacc[2];
  oacc[0] = (floatx4){0.f, 0.f, 0.f, 0.f};
  oacc[1] = (floatx4){0.f, 0.f, 0.f, 0.f};

  auto ldA = [&](int kk, uint4& h0, uint4& h1, uint4& l0, uint4& l1) {
    int ys = y - 1 + kk / 3;
    int xs = xp - 1 + kk % 3;
    bool valid = (ys >= 0) && (ys < HH) && (xs >= 0) && (xs < WW);
    h0 = (uint4){0, 0, 0, 0}; h1 = h0; l0 = h0; l1 = h0;
    if (valid) {
      const unsigned short* ph = xhib + (size_t)(ys * WW + xs) * CIN + si * 16;
      const unsigned short* pl = xlob + (size_t)(ys * WW + xs) * CIN + si * 16;
      h0 = *(const uint4*)ph; h1 = *(const uint4*)(ph + 8);
      l0 = *(const uint4*)pl; l1 = *(const uint4*)(pl + 8);
    }
  };
  auto bodyA = [&](int kk, const uint4& h0, const uint4& h1, const uint4& l0, const uint4& l1) {
    // A-frag loads issued first: latency hides under ds_write + barrier.
    const short8* Ah = (const short8*)(woAhi + (size_t)kk * 2048);
    const short8* Al = (const short8*)(woAlo + (size_t)kk * 2048);
    short8 ah0a = Ah[lane],       ah1a = Ah[128 + lane];
    short8 al0a = Al[lane],       al1a = Al[128 + lane];
    short8 ah0b = Ah[64 + lane],  ah1b = Ah[192 + lane];
    short8 al0b = Al[64 + lane],  al1b = Al[192 + lane];
    *(uint4*)stHi0 = h0; *(uint4*)stHi1 = h1;
    *(uint4*)stLo0 = l0; *(uint4*)stLo1 = l1;
    __syncthreads();
    short8 bh0 = *rdHi0, bh1 = *rdHi1;
    short8 bl0 = *rdLo0, bl1 = *rdLo1;
    oacc[0] = __builtin_amdgcn_mfma_f32_16x16x32_bf16(ah0a, bh0, oacc[0], 0, 0, 0);
    oacc[0] = __builtin_amdgcn_mfma_f32_16x16x32_bf16(ah0a, bl0, oacc[0], 0, 0, 0);
    oacc[0] = __builtin_amdgcn_mfma_f32_16x16x32_bf16(al0a, bh0, oacc[0], 0, 0, 0);
    oacc[0] = __builtin_amdgcn_mfma_f32_16x16x32_bf16(ah1a, bh1, oacc[0], 0, 0, 0);
    oacc[0] = __builtin_amdgcn_mfma_f32_16x16x32_bf16(ah1a, bl1, oacc[0], 0, 0, 0);
    oacc[0] = __builtin_amdgcn_mfma_f32_16x16x32_bf16(al1a, bh1, oacc[0], 0, 0, 0);
    oacc[1] = __builtin_amdgcn_mfma_f32_16x16x32_bf16(ah0b, bh0, oacc[1], 0, 0, 0);
    oacc[1] = __builtin_amdgcn_mfma_f32_16x16x32_bf16(ah0b, bl0, oacc[1], 0, 0, 0);
    oacc[1] = __builtin_amdgcn_mfma_f32_16x16x32_bf16(al0b, bh0, oacc[1], 0, 0, 0);
    oacc[1] = __builtin_amdgcn_mfma_f32_16x16x32_bf16(ah1b, bh1, oacc[1], 0, 0, 0);
    oacc[1] = __builtin_amdgcn_mfma_f32_16x16x32_bf16(ah1b, bl1, oacc[1], 0, 0, 0);
    oacc[1] = __builtin_amdgcn_mfma_f32_16x16x32_bf16(al1b, bh1, oacc[1], 0, 0, 0);
    __syncthreads();
  };

  {
    uint4 h0c, h1c, l0c, l1c;
    ldA(0, h0c, h1c, l0c, l1c);
#pragma unroll 1
    for (int kk = 0; kk < 8; kk++) {
      uint4 h0n, h1n, l0n, l1n;
      ldA(kk + 1, h0n, h1n, l0n, l1n);      // issue next-iter loads
      bodyA(kk, h0c, h1c, l0c, l1c);        // consume current (counted vmcnt)
      h0c = h0n; h1c = h1n; l0c = l0n; l1c = l1n;
    }
    bodyA(8, h0c, h1c, l0c, l1c);
  }

  // Scatter offsets to LDS. D layout: col=lane&15 (px), row=(lane>>4)*4+rr.
  // Wave w writes columns [16w,16w+16) and phase B (p1 in [16w,16w+16)) reads
  // only those -> same-wave ordering, no barrier needed.
  {
    int pxl = w * 16 + (lane & 15);
    int rowb = (lane >> 4) * 4;
#pragma unroll
    for (int ct = 0; ct < 2; ct++)
#pragma unroll
      for (int rr = 0; rr < 4; rr++) {
        int row = ct * 16 + rowb + rr;
        if (row < 18) offL[row * 64 + pxl] = oacc[ct][rr];
      }
  }

  // ================= Phase B: deform sample + GEMM (pipelined) =================
  floatx4 acc[4];
#pragma unroll
  for (int ct = 0; ct < 4; ct++) acc[ct] = (floatx4){0.f, 0.f, 0.f, 0.f};

  struct BS {
    float w00, w01, w10, w11;
    uint4 a00, a01, a10, a11, b00, b01, b10, b11;
  };
  auto ldB = [&](int kk) -> BS {
    BS s;
    float dy = offL[(2 * kk) * 64 + p1];
    float dx = offL[(2 * kk + 1) * 64 + p1];
    float ys = (float)(y - 1 + kk / 3) + dy;
    float xs = (float)(xp - 1 + kk % 3) + dx;
    float y0f = floorf(ys), x0f = floorf(xs);
    float wy = ys - y0f, wx = xs - x0f;
    int iy0 = (int)y0f, ix0 = (int)x0f;
    int iy1 = iy0 + 1, ix1 = ix0 + 1;
    s.w00 = (1.f - wy) * (1.f - wx); s.w01 = (1.f - wy) * wx;
    s.w10 = wy * (1.f - wx);         s.w11 = wy * wx;
    bool vy0 = (iy0 >= 0) && (iy0 < HH), vy1 = (iy1 >= 0) && (iy1 < HH);
    bool vx0 = (ix0 >= 0) && (ix0 < WW), vx1 = (ix1 >= 0) && (ix1 < WW);
    if (!(vy0 && vx0)) s.w00 = 0.f;
    if (!(vy0 && vx1)) s.w01 = 0.f;
    if (!(vy1 && vx0)) s.w10 = 0.f;
    if (!(vy1 && vx1)) s.w11 = 0.f;
    int cy0 = min(max(iy0, 0), HH - 1), cy1 = min(max(iy1, 0), HH - 1);
    int cx0 = min(max(ix0, 0), WW - 1), cx1 = min(max(ix1, 0), WW - 1);
    const unsigned short* q00 = xhib + (size_t)(cy0 * WW + cx0) * CIN + si * 16;
    const unsigned short* q01 = xhib + (size_t)(cy0 * WW + cx1) * CIN + si * 16;
    const unsigned short* q10 = xhib + (size_t)(cy1 * WW + cx0) * CIN + si * 16;
    const unsigned short* q11 = xhib + (size_t)(cy1 * WW + cx1) * CIN + si * 16;
    s.a00 = *(const uint4*)q00; s.a01 = *(const uint4*)q01;
    s.a10 = *(const uint4*)q10; s.a11 = *(const uint4*)q11;
    s.b00 = *(const uint4*)(q00 + 8); s.b01 = *(const uint4*)(q01 + 8);
    s.b10 = *(const uint4*)(q10 + 8); s.b11 = *(const uint4*)(q11 + 8);
    return s;
  };
  auto bodyB = [&](int kk, const BS& s) {
    // A-frag loads issued first: latency hides under blend + barrier.
    const short8* Ap = (const short8*)(wdA + (size_t)kk * 4096);
    short8 a0q0 = Ap[lane],        a1q0 = Ap[256 + lane];
    short8 a0q1 = Ap[64 + lane],   a1q1 = Ap[320 + lane];
    short8 a0q2 = Ap[128 + lane],  a1q2 = Ap[384 + lane];
    short8 a0q3 = Ap[192 + lane],  a1q3 = Ap[448 + lane];
    uint4 o0, o1;
    o0.x = bilin2(s.a00.x, s.a01.x, s.a10.x, s.a11.x, s.w00, s.w01, s.w10, s.w11);
    o0.y = bilin2(s.a00.y, s.a01.y, s.a10.y, s.a11.y, s.w00, s.w01, s.w10, s.w11);
    o0.z = bilin2(s.a00.z, s.a01.z, s.a10.z, s.a11.z, s.w00, s.w01, s.w10, s.w11);
    o0.w = bilin2(s.a00.w, s.a01.w, s.a10.w, s.a11.w, s.w00, s.w01, s.w10, s.w11);
    o1.x = bilin2(s.b00.x, s.b01.x, s.b10.x, s.b11.x, s.w00, s.w01, s.w10, s.w11);
    o1.y = bilin2(s.b00.y, s.b01.y, s.b10.y, s.b11.y, s.w00, s.w01, s.w10, s.w11);
    o1.z = bilin2(s.b00.z, s.b01.z, s.b10.z, s.b11.z, s.w00, s.w01, s.w10, s.w11);
    o1.w = bilin2(s.b00.w, s.b01.w, s.b10.w, s.b11.w, s.w00, s.w01, s.w10, s.w11);
    *(uint4*)stHi0 = o0;
    *(uint4*)stHi1 = o1;
    __syncthreads();
    short8 bv0 = *rdHi0, bv1 = *rdHi1;
    acc[0] = __builtin_amdgcn_mfma_f32_16x16x32_bf16(a0q0, bv0, acc[0], 0, 0, 0);
    acc[0] = __builtin_amdgcn_mfma_f32_16x16x32_bf16(a1q0, bv1, acc[0], 0, 0, 0);
    acc[1] = __builtin_amdgcn_mfma_f32_16x16x32_bf16(a0q1, bv0, acc[1], 0, 0, 0);
    acc[1] = __builtin_amdgcn_mfma_f32_16x16x32_bf16(a1q1, bv1, acc[1], 0, 0, 0);
    acc[2] = __builtin_amdgcn_mfma_f32_16x16x32_bf16(a0q2, bv0, acc[2], 0, 0, 0);
    acc[2] = __builtin_amdgcn_mfma_f32_16x16x32_bf16(a1q2, bv1, acc[2], 0, 0, 0);
    acc[3] = __builtin_amdgcn_mfma_f32_16x16x32_bf16(a0q3, bv0, acc[3], 0, 0, 0);
    acc[3] = __builtin_amdgcn_mfma_f32_16x16x32_bf16(a1q3, bv1, acc[3], 0, 0, 0);
    __syncthreads();
  };

  {
    BS sc = ldB(0);
#pragma unroll 1
    for (int kk = 0; kk < 8; kk++) {
      BS sn = ldB(kk + 1);    // issue next-iter loads (incl. offL LDS reads)
      bodyB(kk, sc);          // blend current (counted vmcnt), stage, MFMA
      sc = sn;
    }
    bodyB(8, sc);
  }

  // D: col = lane&15 (px in wave tile), row = (lane>>4)*4 + reg (cout in ct tile)
  int px = x0 + w * 16 + (lane & 15);
  int rowb = (lane >> 4) * 4;
  float* outb = out + (size_t)b * COUT * HWPIX + y * WW + px;
#pragma unroll
  for (int ct = 0; ct < 4; ct++)
#pragma unroll
    for (int rr = 0; rr < 4; rr++)
      outb[(size_t)(ct * 16 + rowb + rr) * HWPIX] = acc[ct][rr];
}

extern "C" void kernel_launch(void* const* d_in, const int* in_sizes, int n_in,
                              void* d_out, int out_size, void* d_ws, size_t ws_size,
                              hipStream_t stream) {
  const float* x  = (const float*)d_in[0];
  const float* wo = (const float*)d_in[1];
  const float* wd = (const float*)d_in[2];
  float* out = (float*)d_out;

  char* wsb = (char*)d_ws;
  unsigned short* xThi  = (unsigned short*)wsb;                         // 8,388,608 B
  unsigned short* xTlo  = (unsigned short*)(wsb + 8388608);             // 8,388,608 B
  unsigned short* wdA   = (unsigned short*)(wsb + 16777216);            // 73,728 B
  unsigned short* woAhi = (unsigned short*)(wsb + 16777216 + 73728);    // 36,864 B
  unsigned short* woAlo = (unsigned short*)(wsb + 16850944 + 36864);    // 36,864 B

  pre_kernel<<<dim3(4096 + 216), dim3(256), 0, stream>>>(x, wo, wd, xThi, xTlo, wdA, woAhi, woAlo);
  fused_dcn_kernel<<<dim3(BATCH * HWPIX / 64), dim3(256), 0, stream>>>(xThi, xTlo, woAhi, woAlo, wdA, out);
}